// Round 1
// 7977.749 us; speedup vs baseline: 5.9711x; 5.9711x over previous
//
#include <hip/hip_runtime.h>
#include <hip/hip_fp16.h>

// RNN_14078902797083: 2-layer tanh RNN + FC + softmax, fp32 in/out.
// B=64, T=2048, IN=256, H=512, NCLASS=2.
//
// R5: kill the cross-WG exchange entirely. Previous design sharded the
// hidden state across 8 slices x 32 groups and spin-polled agent-scope
// loads every step (FETCH 38.6 GB/dispatch, VALUBusy 9%). Now:
//  - input projection xw = x@Wih^T + bias as parallel fp32 GEMMs
//    (pre-transposed W for coalesced loads), IN PLACE in one 256MB buffer
//  - recurrence: 1 WG per batch (64 WGs), W_hh resident per-CU as fp16:
//    k=0..383 in VGPRs (192 v2f16/thread), k=384..511 in LDS (128 KB),
//    h double-buffered in LDS as packed fp16, v_dot2_f32_f16 accumulate
//    in fp32, tanh fp32. One s_barrier per step, zero global traffic
//    except the xw stream + h writeback.

#define BB 64
#define TT 2048
#define IN 256
#define HH 512
#define MM (BB * TT)          // 131072 rows

// workspace layout (bytes) — identical total to previous proven layout
#define BUF0_OFF 0ull                      // [B][T][H] f32 = 256 MB (xw0 -> h1 -> xw1, in place)
#define WT_OFF   268435456ull              // W^T scratch, 1 MB (WT0 then WT1, disjoint lifetimes)
#define H2L_OFF  269484032ull              // [B][H] f32 last hidden = 128 KB

// ---- recurrent weight split ----
#define KREG 384                 // k-range held in VGPRs (192 packed v2f16)
#define KLDS (HH - KREG)         // 128 -> LDS as uint4 [KLDS/8][HH] = 128 KB
#define NCH_REG (KREG / 8)       // 48 uint4 h-chunks from regs
#define NCH_LDS (KLDS / 8)       // 16 uint4 h-chunks from LDS
#define SCAN_SMEM (NCH_LDS * HH * 16 + 2 * 256 * 4)   // 131072 + 2048 = 133120 B

typedef _Float16 v2h __attribute__((ext_vector_type(2)));

__device__ __forceinline__ float fdot2u(unsigned a, unsigned b, float c) {
#if __has_builtin(__builtin_amdgcn_fdot2)
    union { unsigned u; v2h h; } ua, ub;
    ua.u = a; ub.u = b;
    return __builtin_amdgcn_fdot2(ua.h, ub.h, c, false);
#else
    __half2 ah = *reinterpret_cast<__half2*>(&a);
    __half2 bh = *reinterpret_cast<__half2*>(&b);
    float2 fa = __half22float2(ah), fb = __half22float2(bh);
    return fmaf(fa.y, fb.y, fmaf(fa.x, fb.x, c));
#endif
}

__device__ __forceinline__ unsigned pk2(float x, float y) {
    unsigned lo = (unsigned)__half_as_ushort(__float2half(x));
    unsigned hi = (unsigned)__half_as_ushort(__float2half(y));
    return lo | (hi << 16);
}

// -------------------- W transpose: W[512][K] -> WT[K][512] --------------------
__global__ void transpose_w(const float* __restrict__ W, float* __restrict__ WT, int K)
{
    __shared__ float tile[32][33];
    const int k0 = blockIdx.x * 32;
    const int c0 = blockIdx.y * 32;
    const int tx = threadIdx.x & 31;
    const int ty = threadIdx.x >> 5;          // 0..7
    #pragma unroll
    for (int i = ty; i < 32; i += 8)
        tile[i][tx] = W[(size_t)(c0 + i) * K + k0 + tx];   // coalesced along k
    __syncthreads();
    #pragma unroll
    for (int i = ty; i < 32; i += 8)
        WT[(size_t)(k0 + i) * HH + c0 + tx] = tile[tx][i]; // coalesced along c
}

// -------------------- input projection GEMM: out = A @ W^T + (b1+b2) ----------
// A [M][K] (may alias out), WT [K][512], out [M][512]. 32 rows/WG, full N.
// Full-K A staging in LDS BEFORE any write -> in-place safe per 32-row block.
template <int K>
__global__ __launch_bounds__(256, 2)
void gemm_xw(const float* A, const float* __restrict__ WT,
             const float* __restrict__ b1, const float* __restrict__ b2,
             float* out)
{
    extern __shared__ char smem[];
    float* As = (float*)smem;                 // [32][K]
    const int m0 = blockIdx.x * 32;
    const int tid = threadIdx.x;

    const float* Ab = A + (size_t)m0 * K;
    #pragma unroll
    for (int i = 0; i < (32 * K) / 1024; ++i) {
        const int idx = tid * 4 + i * 1024;
        *(float4*)&As[idx] = *(const float4*)&Ab[idx];
    }
    __syncthreads();

    const int tc = tid & 63;                  // col base lane; cols c = tc + 64*cc
    const int r0 = (tid >> 6) * 8;            // 8 rows per thread

    float acc[8][8];
    #pragma unroll
    for (int cc = 0; cc < 8; ++cc) {
        const int c = tc + 64 * cc;
        const float bb = b1[c] + b2[c];
        #pragma unroll
        for (int rr = 0; rr < 8; ++rr) acc[rr][cc] = bb;
    }

    #pragma unroll 2
    for (int k = 0; k < K; k += 4) {
        float4 av4[8];
        #pragma unroll
        for (int rr = 0; rr < 8; ++rr)
            av4[rr] = *(const float4*)&As[(r0 + rr) * K + k];   // wave-uniform: broadcast
        #pragma unroll
        for (int kk = 0; kk < 4; ++kk) {
            float wv[8];
            #pragma unroll
            for (int cc = 0; cc < 8; ++cc)
                wv[cc] = WT[(size_t)(k + kk) * HH + tc + 64 * cc];  // lane-consecutive: coalesced
            #pragma unroll
            for (int rr = 0; rr < 8; ++rr) {
                const float a = ((const float*)&av4[rr])[kk];
                #pragma unroll
                for (int cc = 0; cc < 8; ++cc)
                    acc[rr][cc] = fmaf(a, wv[cc], acc[rr][cc]);
            }
        }
    }

    #pragma unroll
    for (int rr = 0; rr < 8; ++rr) {
        float* orow = out + (size_t)(m0 + r0 + rr) * HH;
        #pragma unroll
        for (int cc = 0; cc < 8; ++cc)
            orow[tc + 64 * cc] = acc[rr][cc];
    }
}

// -------------------- recurrent scan: one WG per batch, no inter-WG comm ------
template <bool WRITE_SEQ>
__global__ __launch_bounds__(512, 2)
void scan_rnn(const float* xw,                 // [B][T][H]; aliased by hseq when WRITE_SEQ
              const float* __restrict__ Whh,   // [H][H]
              float* hseq)                     // WRITE_SEQ: [B][T][H] (alias of xw); else [B][H]
{
    extern __shared__ char smem[];
    uint4* wlds4   = (uint4*)smem;                              // [NCH_LDS][HH]
    unsigned* hpk  = (unsigned*)(smem + NCH_LDS * HH * 16);     // [2][256] packed fp16 h

    const int b = blockIdx.x;
    const int j = threadIdx.x;                 // output row 0..511

    // ---- one-time: load W_hh row j as packed fp16 ----
    const float* wrow = Whh + (size_t)j * HH;
    unsigned w[KREG / 2];
    #pragma unroll
    for (int q = 0; q < KREG / 2; ++q) {
        float2 f = *(const float2*)(wrow + 2 * q);
        w[q] = pk2(f.x, f.y);
    }
    #pragma unroll
    for (int qq = 0; qq < NCH_LDS; ++qq) {
        const float* p = wrow + KREG + qq * 8;
        uint4 v;
        v.x = pk2(p[0], p[1]); v.y = pk2(p[2], p[3]);
        v.z = pk2(p[4], p[5]); v.w = pk2(p[6], p[7]);
        wlds4[qq * HH + j] = v;                // lane-consecutive uint4: conflict-free
    }
    __syncthreads();

    const float* xrow = xw + (size_t)b * TT * HH + j;
    float* srow = WRITE_SEQ ? (hseq + (size_t)b * TT * HH + j) : nullptr;

    float xw_cur = xrow[0];
    for (int t = 0; t < TT; ++t) {
        const int tn = (t + 1 < TT) ? (t + 1) : t;
        const float xw_next = xrow[(size_t)tn * HH];   // prefetch, overlaps dot phase

        float z = xw_cur;
        if (t > 0) {
            const unsigned* hp = hpk + (((t & 1) ^ 1) * 256);
            float a0 = 0.f, a1 = 0.f, a2 = 0.f, a3 = 0.f;
            #pragma unroll
            for (int c = 0; c < NCH_REG; ++c) {
                const uint4 hv = *(const uint4*)(hp + c * 4);   // uniform addr: LDS broadcast
                a0 = fdot2u(w[c * 4 + 0], hv.x, a0);
                a1 = fdot2u(w[c * 4 + 1], hv.y, a1);
                a2 = fdot2u(w[c * 4 + 2], hv.z, a2);
                a3 = fdot2u(w[c * 4 + 3], hv.w, a3);
            }
            #pragma unroll
            for (int qq = 0; qq < NCH_LDS; ++qq) {
                const uint4 wv = wlds4[qq * HH + j];
                const uint4 hv = *(const uint4*)(hp + NCH_REG * 4 + qq * 4);
                a0 = fdot2u(wv.x, hv.x, a0);
                a1 = fdot2u(wv.y, hv.y, a1);
                a2 = fdot2u(wv.z, hv.z, a2);
                a3 = fdot2u(wv.w, hv.w, a3);
            }
            z += (a0 + a1) + (a2 + a3);
        }
        const float h = tanhf(z);

        // publish h for next step (write buffer != read buffer -> 1 barrier/step)
        ((unsigned short*)(hpk + (t & 1) * 256))[j] = __half_as_ushort(__float2half(h));

        if (WRITE_SEQ) {
            srow[(size_t)t * HH] = h;          // in-place over xw[b][t][j]: thread-local element
        } else if (t == TT - 1) {
            hseq[b * HH + j] = h;
        }
        xw_cur = xw_next;
        __syncthreads();
    }
}

// -------------------- FC + softmax --------------------
__global__ void fc_kernel(const float* __restrict__ h2, const float* __restrict__ w,
                          const float* __restrict__ bvec, float* __restrict__ out)
{
    const int b = threadIdx.x;   // 64 threads
    float z0 = bvec[0], z1 = bvec[1];
    #pragma unroll 4
    for (int k = 0; k < HH; k += 4) {
        float4 h  = *(const float4*)&h2[b * HH + k];
        float4 w0 = *(const float4*)&w[k];
        float4 w1 = *(const float4*)&w[HH + k];
        z0 += h.x * w0.x + h.y * w0.y + h.z * w0.z + h.w * w0.w;
        z1 += h.x * w1.x + h.y * w1.y + h.z * w1.z + h.w * w1.w;
    }
    const float m  = fmaxf(z0, z1);
    const float e0 = expf(z0 - m), e1 = expf(z1 - m);
    const float inv = 1.f / (e0 + e1);
    out[b * 2 + 0] = e0 * inv;
    out[b * 2 + 1] = e1 * inv;
}

extern "C" void kernel_launch(void* const* d_in, const int* in_sizes, int n_in,
                              void* d_out, int out_size, void* d_ws, size_t ws_size,
                              hipStream_t stream)
{
    (void)in_sizes; (void)n_in; (void)out_size; (void)ws_size;
    const float* x    = (const float*)d_in[0];
    const float* Wih0 = (const float*)d_in[1];
    const float* Whh0 = (const float*)d_in[2];
    const float* bih0 = (const float*)d_in[3];
    const float* bhh0 = (const float*)d_in[4];
    const float* Wih1 = (const float*)d_in[5];
    const float* Whh1 = (const float*)d_in[6];
    const float* bih1 = (const float*)d_in[7];
    const float* bhh1 = (const float*)d_in[8];
    const float* fcw  = (const float*)d_in[9];
    const float* fcb  = (const float*)d_in[10];
    float* out = (float*)d_out;

    char* ws = (char*)d_ws;
    float* buf0 = (float*)(ws + BUF0_OFF);
    float* WT   = (float*)(ws + WT_OFF);
    float* h2l  = (float*)(ws + H2L_OFF);

    static bool attr_done = false;
    if (!attr_done) {
        hipFuncSetAttribute((const void*)scan_rnn<true>,
                            hipFuncAttributeMaxDynamicSharedMemorySize, SCAN_SMEM);
        hipFuncSetAttribute((const void*)scan_rnn<false>,
                            hipFuncAttributeMaxDynamicSharedMemorySize, SCAN_SMEM);
        attr_done = true;
    }

    // ---- layer 0 ----
    transpose_w<<<dim3(IN / 32, HH / 32), dim3(256), 0, stream>>>(Wih0, WT, IN);
    gemm_xw<IN><<<dim3(MM / 32), dim3(256), 32 * IN * 4, stream>>>(x, WT, bih0, bhh0, buf0);
    scan_rnn<true><<<dim3(BB), dim3(512), SCAN_SMEM, stream>>>(buf0, Whh0, buf0);

    // ---- layer 1 (WT buffer reused: lifetimes disjoint) ----
    transpose_w<<<dim3(HH / 32, HH / 32), dim3(256), 0, stream>>>(Wih1, WT, HH);
    gemm_xw<HH><<<dim3(MM / 32), dim3(256), 32 * HH * 4, stream>>>(buf0, WT, bih1, bhh1, buf0);
    scan_rnn<false><<<dim3(BB), dim3(512), SCAN_SMEM, stream>>>(buf0, Whh1, h2l);

    // ---- FC + softmax ----
    fc_kernel<<<dim3(1), dim3(64), 0, stream>>>(h2l, fcw, fcb, out);
}